// Round 8
// baseline (265.907 us; speedup 1.0000x reference)
//
#include <hip/hip_runtime.h>

#define NUSER 100000
#define NITEM 150000
#define NBRAND 5000
#define NNODES (NUSER + NITEM + NBRAND)   // 255000
#define DIM 64
#define NOUTROWS (NUSER + NITEM)          // 250000

#define BINSHIFT 10
#define NBINS ((NNODES + (1 << BINSHIFT) - 1) >> BINSHIFT)   // 250
#define EPB_A 8192        // edges per binA block (8 per thread @ 1024 thr)
#define CAP 12288         // colval/binned capacity per bin (expected 8000 +/- 90)
#define RPS 1025          // rowptr entries per bin (1024 rows + end sentinel)

// bf16 helpers (manual, RNE rounding)
__device__ __forceinline__ float bf2f(unsigned short u) {
    union { unsigned int i; float f; } c;
    c.i = ((unsigned int)u) << 16;
    return c.f;
}
__device__ __forceinline__ unsigned short f2bf(float f) {
    union { float f; unsigned int i; } c;
    c.f = f;
    unsigned int r = c.i + 0x7FFFu + ((c.i >> 16) & 1u);
    return (unsigned short)(r >> 16);
}

// ============================ CSR build =====================================
// Phase A: counting sort into 250 fixed-capacity row-bins (region b*CAP).
// 1024 threads/block (16 waves) for occupancy; row ids cached in registers.
__global__ __launch_bounds__(1024) void lgcn_binA(const int* __restrict__ rows,
                                                  const int* __restrict__ cols,
                                                  const float* __restrict__ vals,
                                                  int* __restrict__ binCnt,
                                                  int2* __restrict__ binned,
                                                  int nedges) {
    __shared__ int hist[NBINS];
    __shared__ int base[NBINS];
    int t = threadIdx.x;
    for (int i = t; i < NBINS; i += 1024) hist[i] = 0;
    __syncthreads();
    int beg = blockIdx.x * EPB_A;
    int end = beg + EPB_A;
    if (end > nedges) end = nedges;
    int r[8];
    #pragma unroll
    for (int k = 0; k < 8; ++k) {
        int e = beg + t + k * 1024;
        r[k] = (e < end) ? rows[e] : -1;
        if (r[k] >= 0) atomicAdd(&hist[r[k] >> BINSHIFT], 1);
    }
    __syncthreads();
    for (int i = t; i < NBINS; i += 1024) {
        int h = hist[i];
        base[i] = h ? (i * CAP + atomicAdd(&binCnt[i], h)) : 0;
        hist[i] = 0;                       // reuse as within-block position
    }
    __syncthreads();
    #pragma unroll
    for (int k = 0; k < 8; ++k) {
        if (r[k] >= 0) {
            int e = beg + t + k * 1024;
            int b = r[k] >> BINSHIFT;
            int pos = base[b] + atomicAdd(&hist[b], 1);
            int2 p;
            p.x = ((r[k] & 1023) << 18) | cols[e];
            p.y = __float_as_int(vals[e]);
            binned[pos] = p;
        }
    }
}

// Phase B: one 1024-thread block per bin. Per-row histogram (1 row/thread),
// 1024-wide exclusive scan in LDS, rowptr (per-bin layout) written directly,
// scatter via LDS cursors into the bin's region of colval. No global scan.
__global__ __launch_bounds__(1024) void lgcn_binB(const int* __restrict__ binCnt,
                                                  const int2* __restrict__ binned,
                                                  int2* __restrict__ colval,
                                                  int* __restrict__ rowptr) {
    __shared__ int lhist[1024];
    __shared__ int part[1024];
    __shared__ int lcur[1024];
    int b = blockIdx.x;
    int t = threadIdx.x;
    int cnt = binCnt[b];
    lhist[t] = 0;
    __syncthreads();
    const int2* bsrc = binned + (size_t)b * CAP;
    for (int e = t; e < cnt; e += 1024) {
        atomicAdd(&lhist[bsrc[e].x >> 18], 1);
    }
    __syncthreads();
    int h = lhist[t];
    part[t] = h;
    __syncthreads();
    for (int off = 1; off < 1024; off <<= 1) {
        int v = (t >= off) ? part[t - off] : 0;
        __syncthreads();
        part[t] += v;
        __syncthreads();
    }
    int c = b * CAP + part[t] - h;         // exclusive prefix within bin
    lcur[t] = c;
    rowptr[b * RPS + t] = c;               // rows beyond NNODES: harmless
    if (t == 1023) rowptr[b * RPS + 1024] = b * CAP + cnt;
    __syncthreads();
    for (int e = t; e < cnt; e += 1024) {
        int2 p = bsrc[e];
        int pos = atomicAdd(&lcur[p.x >> 18], 1);
        int2 cv;
        cv.x = p.x & 0x3FFFF;
        cv.y = p.y;
        colval[pos] = cv;
    }
}

// ============================ init / spmm ===================================

// convert f32 inputs -> bf16 x0 (row-major [NNODES][64])
__global__ __launch_bounds__(256) void lgcn_init(const float4* __restrict__ u,
                                                 const float4* __restrict__ it,
                                                 const float4* __restrict__ br,
                                                 ushort4* __restrict__ x0b) {
    int i = blockIdx.x * blockDim.x + threadIdx.x;
    const int total = NNODES * (DIM / 4);
    if (i >= total) return;
    float4 v;
    if (i < NUSER * (DIM / 4)) {
        v = u[i];
    } else if (i < (NUSER + NITEM) * (DIM / 4)) {
        v = it[i - NUSER * (DIM / 4)];
    } else {
        v = br[i - (NUSER + NITEM) * (DIM / 4)];
    }
    ushort4 o;
    o.x = f2bf(v.x); o.y = f2bf(v.y); o.z = f2bf(v.z); o.w = f2bf(v.w);
    x0b[i] = o;
}

// CSR SpMM over bf16 state. 16 lanes per group, 2 rows per group, lane handles
// 4 contiguous dims. Predicated-8 pipeline per row -> ~16 gathers in flight
// (dummy slots clamp to a valid index with val=0: L1-hit, free).
// Non-final: write y (bf16). FINAL: out = (x0b + y1 + y2 + s) * 0.25.
template <bool FINAL>
__global__ __launch_bounds__(256) void lgcn_spmm_csr(const int* __restrict__ rowptr,
                                                     const int2* __restrict__ colval,
                                                     const ushort4* __restrict__ xb,
                                                     ushort4* __restrict__ yb,
                                                     const ushort4* __restrict__ x0b,
                                                     const ushort4* __restrict__ y1b,
                                                     const ushort4* __restrict__ y2b,
                                                     float4* __restrict__ out) {
    int t = blockIdx.x * blockDim.x + threadIdx.x;
    int g = t >> 4;
    int l = t & 15;
    int row0 = g * 2;
    int row1 = row0 + 1;
    const int LIMIT = FINAL ? NOUTROWS : NNODES;
    if (row0 >= LIMIT) return;                    // LIMIT even -> row1 ok too
    int i0 = (row0 >> BINSHIFT) * RPS + (row0 & 1023);
    int i1 = (row1 >> BINSHIFT) * RPS + (row1 & 1023);
    int beg0 = rowptr[i0], end0 = rowptr[i0 + 1];
    int beg1 = rowptr[i1], end1 = rowptr[i1 + 1];
    int safe0 = (beg0 < end0) ? beg0 : 0;
    int safe1 = (beg1 < end1) ? beg1 : 0;
    float4 s0 = make_float4(0.f, 0.f, 0.f, 0.f);
    float4 s1 = make_float4(0.f, 0.f, 0.f, 0.f);
    int p0 = beg0, p1 = beg1;
    while (p0 < end0 || p1 < end1) {
        int2 cv0[8], cv1[8];
        #pragma unroll
        for (int k = 0; k < 8; ++k) { int q = p0 + k; cv0[k] = colval[q < end0 ? q : safe0]; }
        #pragma unroll
        for (int k = 0; k < 8; ++k) { int q = p1 + k; cv1[k] = colval[q < end1 ? q : safe1]; }
        ushort4 a0[8], a1[8];
        #pragma unroll
        for (int k = 0; k < 8; ++k) a0[k] = xb[(size_t)cv0[k].x * (DIM / 4) + l];
        #pragma unroll
        for (int k = 0; k < 8; ++k) a1[k] = xb[(size_t)cv1[k].x * (DIM / 4) + l];
        #pragma unroll
        for (int k = 0; k < 8; ++k) {
            float v = (p0 + k < end0) ? __int_as_float(cv0[k].y) : 0.f;
            s0.x += v * bf2f(a0[k].x); s0.y += v * bf2f(a0[k].y);
            s0.z += v * bf2f(a0[k].z); s0.w += v * bf2f(a0[k].w);
        }
        #pragma unroll
        for (int k = 0; k < 8; ++k) {
            float v = (p1 + k < end1) ? __int_as_float(cv1[k].y) : 0.f;
            s1.x += v * bf2f(a1[k].x); s1.y += v * bf2f(a1[k].y);
            s1.z += v * bf2f(a1[k].z); s1.w += v * bf2f(a1[k].w);
        }
        p0 += 8; p1 += 8;
    }
    size_t off0 = (size_t)row0 * (DIM / 4) + l;
    size_t off1 = (size_t)row1 * (DIM / 4) + l;
    if (!FINAL) {
        ushort4 o0, o1;
        o0.x = f2bf(s0.x); o0.y = f2bf(s0.y); o0.z = f2bf(s0.z); o0.w = f2bf(s0.w);
        o1.x = f2bf(s1.x); o1.y = f2bf(s1.y); o1.z = f2bf(s1.z); o1.w = f2bf(s1.w);
        yb[off0] = o0;
        yb[off1] = o1;
    } else {
        ushort4 x00 = x0b[off0], a10 = y1b[off0], a20 = y2b[off0];
        ushort4 x01 = x0b[off1], a11 = y1b[off1], a21 = y2b[off1];
        float4 r0, r1;
        r0.x = (bf2f(x00.x) + bf2f(a10.x) + bf2f(a20.x) + s0.x) * 0.25f;
        r0.y = (bf2f(x00.y) + bf2f(a10.y) + bf2f(a20.y) + s0.y) * 0.25f;
        r0.z = (bf2f(x00.z) + bf2f(a10.z) + bf2f(a20.z) + s0.z) * 0.25f;
        r0.w = (bf2f(x00.w) + bf2f(a10.w) + bf2f(a20.w) + s0.w) * 0.25f;
        r1.x = (bf2f(x01.x) + bf2f(a11.x) + bf2f(a21.x) + s1.x) * 0.25f;
        r1.y = (bf2f(x01.y) + bf2f(a11.y) + bf2f(a21.y) + s1.y) * 0.25f;
        r1.z = (bf2f(x01.z) + bf2f(a11.z) + bf2f(a21.z) + s1.z) * 0.25f;
        r1.w = (bf2f(x01.w) + bf2f(a11.w) + bf2f(a21.w) + s1.w) * 0.25f;
        out[off0] = r0;
        out[off1] = r1;
    }
}

// ============================ launch ========================================

static inline size_t align256(size_t x) { return (x + 255) & ~(size_t)255; }

extern "C" void kernel_launch(void* const* d_in, const int* in_sizes, int n_in,
                              void* d_out, int out_size, void* d_ws, size_t ws_size,
                              hipStream_t stream) {
    const float4* u  = (const float4*)d_in[0];
    const float4* it = (const float4*)d_in[1];
    const float4* br = (const float4*)d_in[2];
    const int*   rows = (const int*)d_in[3];
    const int*   cols = (const int*)d_in[4];
    const float* vals = (const float*)d_in[5];
    const int nedges = in_sizes[3];
    float4* out = (float4*)d_out;

    // workspace layout
    char* ws = (char*)d_ws;
    size_t o = 0;
    ushort4* x0b   = (ushort4*)(ws + o); o = align256(o + (size_t)NNODES * DIM * 2);
    ushort4* y1b   = (ushort4*)(ws + o); o = align256(o + (size_t)NNODES * DIM * 2);
    ushort4* y2b   = (ushort4*)(ws + o); o = align256(o + (size_t)NNODES * DIM * 2);
    int*   rowptr  = (int*)(ws + o);     o = align256(o + (size_t)NBINS * RPS * 4);
    int*   binCnt  = (int*)(ws + o);     o = align256(o + 256 * 4);
    int2*  colval  = (int2*)(ws + o);    o = align256(o + (size_t)NBINS * CAP * 8);

    // binned intermediate aliases y1b (dead until spmm1; stream-ordered)
    // size: NBINS * CAP * 8 B = 24.6 MB < 32.6 MB of y1b
    int2* binned = (int2*)y1b;

    const int vecTotal = NNODES * (DIM / 4);
    const int vecBlocks = (vecTotal + 255) / 256;
    const int spmmBlocks  = ((NNODES / 2) * 16 + 255) / 256;
    const int finalBlocks = ((NOUTROWS / 2) * 16 + 255) / 256;
    const int binABlocks = (nedges + EPB_A - 1) / EPB_A;

    // --- CSR build (per-bin layout, no global scan) ---
    hipMemsetAsync(binCnt, 0, 256 * 4, stream);
    lgcn_binA<<<binABlocks, 1024, 0, stream>>>(rows, cols, vals, binCnt, binned, nedges);
    lgcn_binB<<<NBINS, 1024, 0, stream>>>(binCnt, binned, colval, rowptr);

    // --- init: f32 inputs -> bf16 x0 ---
    lgcn_init<<<vecBlocks, 256, 0, stream>>>(u, it, br, x0b);

    // --- 3 propagation layers ---
    lgcn_spmm_csr<false><<<spmmBlocks, 256, 0, stream>>>(rowptr, colval, x0b, y1b,
                                                         nullptr, nullptr, nullptr, nullptr);
    lgcn_spmm_csr<false><<<spmmBlocks, 256, 0, stream>>>(rowptr, colval, y1b, y2b,
                                                         nullptr, nullptr, nullptr, nullptr);
    lgcn_spmm_csr<true><<<finalBlocks, 256, 0, stream>>>(rowptr, colval, y2b, nullptr,
                                                         x0b, y1b, y2b, out);
}

// Round 9
// 230.987 us; speedup vs baseline: 1.1512x; 1.1512x over previous
//
#include <hip/hip_runtime.h>

#define NUSER 100000
#define NITEM 150000
#define NBRAND 5000
#define NNODES (NUSER + NITEM + NBRAND)   // 255000
#define DIM 64
#define NOUTROWS (NUSER + NITEM)          // 250000

#define BINSHIFT 10
#define NBINS ((NNODES + (1 << BINSHIFT) - 1) >> BINSHIFT)   // 250
#define EPB_A 8192        // edges per binA block (8 per thread @ 1024 thr)
#define CAP 12288         // colval/binned capacity per bin (expected 8000 +/- 90)
#define RPS 1025          // rowptr entries per bin (1024 rows + end sentinel)

// bf16 helpers (manual, RNE rounding)
__device__ __forceinline__ float bf2f(unsigned short u) {
    union { unsigned int i; float f; } c;
    c.i = ((unsigned int)u) << 16;
    return c.f;
}
__device__ __forceinline__ unsigned short f2bf(float f) {
    union { float f; unsigned int i; } c;
    c.f = f;
    unsigned int r = c.i + 0x7FFFu + ((c.i >> 16) & 1u);
    return (unsigned short)(r >> 16);
}

// ============================ CSR build =====================================
// Phase A: counting sort into 250 fixed-capacity row-bins (region b*CAP).
// 1024 threads/block (16 waves) for occupancy; row ids cached in registers.
__global__ __launch_bounds__(1024) void lgcn_binA(const int* __restrict__ rows,
                                                  const int* __restrict__ cols,
                                                  const float* __restrict__ vals,
                                                  int* __restrict__ binCnt,
                                                  int2* __restrict__ binned,
                                                  int nedges) {
    __shared__ int hist[NBINS];
    __shared__ int base[NBINS];
    int t = threadIdx.x;
    for (int i = t; i < NBINS; i += 1024) hist[i] = 0;
    __syncthreads();
    int beg = blockIdx.x * EPB_A;
    int end = beg + EPB_A;
    if (end > nedges) end = nedges;
    int r[8];
    #pragma unroll
    for (int k = 0; k < 8; ++k) {
        int e = beg + t + k * 1024;
        r[k] = (e < end) ? rows[e] : -1;
        if (r[k] >= 0) atomicAdd(&hist[r[k] >> BINSHIFT], 1);
    }
    __syncthreads();
    for (int i = t; i < NBINS; i += 1024) {
        int h = hist[i];
        base[i] = h ? (i * CAP + atomicAdd(&binCnt[i], h)) : 0;
        hist[i] = 0;                       // reuse as within-block position
    }
    __syncthreads();
    #pragma unroll
    for (int k = 0; k < 8; ++k) {
        if (r[k] >= 0) {
            int e = beg + t + k * 1024;
            int b = r[k] >> BINSHIFT;
            int pos = base[b] + atomicAdd(&hist[b], 1);
            int2 p;
            p.x = ((r[k] & 1023) << 18) | cols[e];
            p.y = __float_as_int(vals[e]);
            binned[pos] = p;
        }
    }
}

// Phase B: one 1024-thread block per bin. Per-row histogram (1 row/thread),
// 1024-wide exclusive scan in LDS, rowptr (per-bin layout) written directly,
// scatter via LDS cursors into the bin's region of colval. No global scan.
__global__ __launch_bounds__(1024) void lgcn_binB(const int* __restrict__ binCnt,
                                                  const int2* __restrict__ binned,
                                                  int2* __restrict__ colval,
                                                  int* __restrict__ rowptr) {
    __shared__ int lhist[1024];
    __shared__ int part[1024];
    __shared__ int lcur[1024];
    int b = blockIdx.x;
    int t = threadIdx.x;
    int cnt = binCnt[b];
    lhist[t] = 0;
    __syncthreads();
    const int2* bsrc = binned + (size_t)b * CAP;
    for (int e = t; e < cnt; e += 1024) {
        atomicAdd(&lhist[bsrc[e].x >> 18], 1);
    }
    __syncthreads();
    int h = lhist[t];
    part[t] = h;
    __syncthreads();
    for (int off = 1; off < 1024; off <<= 1) {
        int v = (t >= off) ? part[t - off] : 0;
        __syncthreads();
        part[t] += v;
        __syncthreads();
    }
    int c = b * CAP + part[t] - h;         // exclusive prefix within bin
    lcur[t] = c;
    rowptr[b * RPS + t] = c;               // rows beyond NNODES: harmless
    if (t == 1023) rowptr[b * RPS + 1024] = b * CAP + cnt;
    __syncthreads();
    for (int e = t; e < cnt; e += 1024) {
        int2 p = bsrc[e];
        int pos = atomicAdd(&lcur[p.x >> 18], 1);
        int2 cv;
        cv.x = p.x & 0x3FFFF;
        cv.y = p.y;
        colval[pos] = cv;
    }
}

// ============================ init / spmm ===================================

// convert f32 inputs -> bf16 x0 (row-major [NNODES][64])
__global__ __launch_bounds__(256) void lgcn_init(const float4* __restrict__ u,
                                                 const float4* __restrict__ it,
                                                 const float4* __restrict__ br,
                                                 ushort4* __restrict__ x0b) {
    int i = blockIdx.x * blockDim.x + threadIdx.x;
    const int total = NNODES * (DIM / 4);
    if (i >= total) return;
    float4 v;
    if (i < NUSER * (DIM / 4)) {
        v = u[i];
    } else if (i < (NUSER + NITEM) * (DIM / 4)) {
        v = it[i - NUSER * (DIM / 4)];
    } else {
        v = br[i - (NUSER + NITEM) * (DIM / 4)];
    }
    ushort4 o;
    o.x = f2bf(v.x); o.y = f2bf(v.y); o.z = f2bf(v.z); o.w = f2bf(v.w);
    x0b[i] = o;
}

// CSR SpMM over bf16 state. One row per 16-lane group, lane handles 4
// contiguous dims. 8/4/2/1 staircase: exec-masked tail (no dummy issue).
// Per-bin rowptr layout. Non-final: write y (bf16). FINAL: out =
// (x0b + y1 + y2 + s) * 0.25 (f32), user+item rows only.
template <bool FINAL>
__global__ __launch_bounds__(256) void lgcn_spmm_csr(const int* __restrict__ rowptr,
                                                     const int2* __restrict__ colval,
                                                     const ushort4* __restrict__ xb,
                                                     ushort4* __restrict__ yb,
                                                     const ushort4* __restrict__ x0b,
                                                     const ushort4* __restrict__ y1b,
                                                     const ushort4* __restrict__ y2b,
                                                     float4* __restrict__ out) {
    int t = blockIdx.x * blockDim.x + threadIdx.x;
    int row = t >> 4;
    int l = t & 15;
    if (FINAL) { if (row >= NOUTROWS) return; }
    else       { if (row >= NNODES) return; }
    int ri = (row >> BINSHIFT) * RPS + (row & 1023);
    int beg = rowptr[ri];
    int end = rowptr[ri + 1];
    float4 s = make_float4(0.f, 0.f, 0.f, 0.f);
    int p = beg;
    while (p + 8 <= end) {
        int2 cv[8];
        ushort4 a[8];
        #pragma unroll
        for (int k = 0; k < 8; ++k) cv[k] = colval[p + k];
        #pragma unroll
        for (int k = 0; k < 8; ++k) a[k] = xb[(size_t)cv[k].x * (DIM / 4) + l];
        #pragma unroll
        for (int k = 0; k < 8; ++k) {
            float v = __int_as_float(cv[k].y);
            s.x += v * bf2f(a[k].x); s.y += v * bf2f(a[k].y);
            s.z += v * bf2f(a[k].z); s.w += v * bf2f(a[k].w);
        }
        p += 8;
    }
    if (p + 4 <= end) {
        int2 cv[4];
        ushort4 a[4];
        #pragma unroll
        for (int k = 0; k < 4; ++k) cv[k] = colval[p + k];
        #pragma unroll
        for (int k = 0; k < 4; ++k) a[k] = xb[(size_t)cv[k].x * (DIM / 4) + l];
        #pragma unroll
        for (int k = 0; k < 4; ++k) {
            float v = __int_as_float(cv[k].y);
            s.x += v * bf2f(a[k].x); s.y += v * bf2f(a[k].y);
            s.z += v * bf2f(a[k].z); s.w += v * bf2f(a[k].w);
        }
        p += 4;
    }
    if (p + 2 <= end) {
        int2 cv0 = colval[p];
        int2 cv1 = colval[p + 1];
        ushort4 a0 = xb[(size_t)cv0.x * (DIM / 4) + l];
        ushort4 a1 = xb[(size_t)cv1.x * (DIM / 4) + l];
        float v0 = __int_as_float(cv0.y);
        float v1 = __int_as_float(cv1.y);
        s.x += v0 * bf2f(a0.x); s.y += v0 * bf2f(a0.y);
        s.z += v0 * bf2f(a0.z); s.w += v0 * bf2f(a0.w);
        s.x += v1 * bf2f(a1.x); s.y += v1 * bf2f(a1.y);
        s.z += v1 * bf2f(a1.z); s.w += v1 * bf2f(a1.w);
        p += 2;
    }
    if (p < end) {
        int2 cv = colval[p];
        ushort4 a = xb[(size_t)cv.x * (DIM / 4) + l];
        float v = __int_as_float(cv.y);
        s.x += v * bf2f(a.x); s.y += v * bf2f(a.y);
        s.z += v * bf2f(a.z); s.w += v * bf2f(a.w);
    }
    size_t off = (size_t)row * (DIM / 4) + l;
    if (!FINAL) {
        ushort4 o;
        o.x = f2bf(s.x); o.y = f2bf(s.y); o.z = f2bf(s.z); o.w = f2bf(s.w);
        yb[off] = o;
    } else {
        ushort4 x0 = x0b[off];
        ushort4 a1 = y1b[off];
        ushort4 a2 = y2b[off];
        float4 r;
        r.x = (bf2f(x0.x) + bf2f(a1.x) + bf2f(a2.x) + s.x) * 0.25f;
        r.y = (bf2f(x0.y) + bf2f(a1.y) + bf2f(a2.y) + s.y) * 0.25f;
        r.z = (bf2f(x0.z) + bf2f(a1.z) + bf2f(a2.z) + s.z) * 0.25f;
        r.w = (bf2f(x0.w) + bf2f(a1.w) + bf2f(a2.w) + s.w) * 0.25f;
        out[off] = r;
    }
}

// ============================ launch ========================================

static inline size_t align256(size_t x) { return (x + 255) & ~(size_t)255; }

extern "C" void kernel_launch(void* const* d_in, const int* in_sizes, int n_in,
                              void* d_out, int out_size, void* d_ws, size_t ws_size,
                              hipStream_t stream) {
    const float4* u  = (const float4*)d_in[0];
    const float4* it = (const float4*)d_in[1];
    const float4* br = (const float4*)d_in[2];
    const int*   rows = (const int*)d_in[3];
    const int*   cols = (const int*)d_in[4];
    const float* vals = (const float*)d_in[5];
    const int nedges = in_sizes[3];
    float4* out = (float4*)d_out;

    // workspace layout
    char* ws = (char*)d_ws;
    size_t o = 0;
    ushort4* x0b   = (ushort4*)(ws + o); o = align256(o + (size_t)NNODES * DIM * 2);
    ushort4* y1b   = (ushort4*)(ws + o); o = align256(o + (size_t)NNODES * DIM * 2);
    ushort4* y2b   = (ushort4*)(ws + o); o = align256(o + (size_t)NNODES * DIM * 2);
    int*   rowptr  = (int*)(ws + o);     o = align256(o + (size_t)NBINS * RPS * 4);
    int*   binCnt  = (int*)(ws + o);     o = align256(o + 256 * 4);
    int2*  colval  = (int2*)(ws + o);    o = align256(o + (size_t)NBINS * CAP * 8);

    // binned intermediate aliases y1b (dead until spmm1; stream-ordered)
    // size: NBINS * CAP * 8 B = 24.6 MB < 32.6 MB of y1b
    int2* binned = (int2*)y1b;

    const int vecTotal = NNODES * (DIM / 4);
    const int vecBlocks = (vecTotal + 255) / 256;
    const int spmmBlocks  = (NNODES * 16 + 255) / 256;
    const int finalBlocks = (NOUTROWS * 16 + 255) / 256;
    const int binABlocks = (nedges + EPB_A - 1) / EPB_A;

    // --- CSR build (per-bin layout, no global scan) ---
    hipMemsetAsync(binCnt, 0, 256 * 4, stream);
    lgcn_binA<<<binABlocks, 1024, 0, stream>>>(rows, cols, vals, binCnt, binned, nedges);
    lgcn_binB<<<NBINS, 1024, 0, stream>>>(binCnt, binned, colval, rowptr);

    // --- init: f32 inputs -> bf16 x0 ---
    lgcn_init<<<vecBlocks, 256, 0, stream>>>(u, it, br, x0b);

    // --- 3 propagation layers ---
    lgcn_spmm_csr<false><<<spmmBlocks, 256, 0, stream>>>(rowptr, colval, x0b, y1b,
                                                         nullptr, nullptr, nullptr, nullptr);
    lgcn_spmm_csr<false><<<spmmBlocks, 256, 0, stream>>>(rowptr, colval, y1b, y2b,
                                                         nullptr, nullptr, nullptr, nullptr);
    lgcn_spmm_csr<true><<<finalBlocks, 256, 0, stream>>>(rowptr, colval, y2b, nullptr,
                                                         x0b, y1b, y2b, out);
}